// Round 2
// 421.555 us; speedup vs baseline: 1.1349x; 1.1349x over previous
//
#include <hip/hip_runtime.h>
#include <hip/hip_bf16.h>

typedef unsigned short u16;
typedef unsigned int u32;
typedef __attribute__((ext_vector_type(8))) short short8;   // 8 bf16 MFMA frag
typedef __attribute__((ext_vector_type(4))) short short4v;  // 4 bf16
typedef __attribute__((ext_vector_type(4))) float floatx4;  // MFMA C/D frag

#define BB 8
#define LL 1024
#define DD 1024
#define HH 16
#define DHH 64
#define NEGBIG (-3.0e38f)

__device__ inline u16 f2b(float f) {
  union { __hip_bfloat16 h; u16 u; } cv;
  cv.h = __float2bfloat16(f);  // RNE
  return cv.u;
}
__device__ inline float b2f(u16 u) {
  union { u16 u; __hip_bfloat16 h; } cv;
  cv.u = u;
  return __bfloat162float(cv.h);
}
__device__ inline float fin(float v, float sentinel) {
  return (fabsf(v) < 1e30f) ? v : sentinel;
}
// async global->LDS, 16B/lane; LDS dst = wave-uniform base (+lane*16 implicit)
__device__ inline void async16(const void* g, void* l) {
  __builtin_amdgcn_global_load_lds(
      (__attribute__((address_space(1))) void*)(const_cast<void*>(g)),
      (__attribute__((address_space(3))) void*)l, 16, 0, 0);
}

// ===========================================================================
// FAST PATH
// ===========================================================================

// Prep: f32->bf16 conversions (jobs 0..6) + mask bit-pack (7) + amask pack (8)
__global__ __launch_bounds__(256) void convpack(
    const float* __restrict__ key, const float* __restrict__ value,
    const float* __restrict__ query, const float* __restrict__ Wk,
    const float* __restrict__ Wv, const float* __restrict__ Wq,
    const float* __restrict__ Wo, const int* __restrict__ mask,
    const int* __restrict__ amask, u16* __restrict__ keyb,
    u16* __restrict__ valb, u16* __restrict__ qryb, u16* __restrict__ Wkb,
    u16* __restrict__ Wvb, u16* __restrict__ Wqb, u16* __restrict__ Wob,
    u32* __restrict__ maskb, u32* __restrict__ amaskb) {
  const int job = blockIdx.y;
  const int gtid = blockIdx.x * 256 + threadIdx.x;
  const int stride = gridDim.x * 256;

  if (job < 7) {
    const float* src; u16* dst; size_t n4;
    switch (job) {
      case 0: src = key;   dst = keyb; n4 = (size_t)BB * LL * DD / 4; break;
      case 1: src = value; dst = valb; n4 = (size_t)BB * LL * DD / 4; break;
      case 2: src = query; dst = qryb; n4 = (size_t)BB * LL * DD / 4; break;
      case 3: src = Wk;    dst = Wkb;  n4 = (size_t)DD * DD / 4; break;
      case 4: src = Wv;    dst = Wvb;  n4 = (size_t)DD * DD / 4; break;
      case 5: src = Wq;    dst = Wqb;  n4 = (size_t)DD * DD / 4; break;
      default: src = Wo;   dst = Wob;  n4 = (size_t)DD * DD / 4; break;
    }
    for (size_t i = gtid; i < n4; i += stride) {
      float4 v = ((const float4*)src)[i];
      short4v s;
      s[0] = (short)f2b(v.x); s[1] = (short)f2b(v.y);
      s[2] = (short)f2b(v.z); s[3] = (short)f2b(v.w);
      *(short4v*)(dst + i * 4) = s;
    }
  } else if (job == 7) {
    const size_t nw = (size_t)BB * LL * LL / 32;  // 262144 words
    for (size_t w = gtid; w < nw; w += stride) {
      const int4* src = (const int4*)(mask + w * 32);
      u32 bits = 0;
#pragma unroll
      for (int c = 0; c < 8; c++) {
        int4 v = src[c];
        bits |= (u32)(v.x != 0) << (c * 4);
        bits |= (u32)(v.y != 0) << (c * 4 + 1);
        bits |= (u32)(v.z != 0) << (c * 4 + 2);
        bits |= (u32)(v.w != 0) << (c * 4 + 3);
      }
      maskb[w] = bits;
    }
  } else {
    const int nw = BB * LL / 32;  // 256 words
    for (int w = gtid; w < nw; w += stride) {
      const int4* src = (const int4*)(amask + w * 32);
      u32 bits = 0;
#pragma unroll
      for (int c = 0; c < 8; c++) {
        int4 v = src[c];
        bits |= (u32)(v.x != 0) << (c * 4);
        bits |= (u32)(v.y != 0) << (c * 4 + 1);
        bits |= (u32)(v.z != 0) << (c * 4 + 2);
        bits |= (u32)(v.w != 0) << (c * 4 + 3);
      }
      amaskb[w] = bits;
    }
  }
}

// bf16 GEMM, async16 staging. OUT 0: bf16 (B,H,L,DH) | 2: bf16 (B,H,DH,L) | 1: f32 row-major
template <int OUT>
__global__ __launch_bounds__(256) void gemm_b(
    const u16* __restrict__ A, const u16* __restrict__ Wb,
    const float* __restrict__ bias, void* __restrict__ outv, float scale) {
  __shared__ u16 As[128 * 32];
  __shared__ u16 Ws[128 * 32];

  const int tid = threadIdx.x;
  const int wave = tid >> 6, lane = tid & 63;
  const int lr = lane & 15, lq = lane >> 4;
  const int row0 = blockIdx.x * 128;
  const int col0 = blockIdx.y * 128;
  const int wm = (wave & 1) * 64, wn = (wave >> 1) * 64;

  floatx4 acc[4][4];
#pragma unroll
  for (int i = 0; i < 4; i++)
#pragma unroll
    for (int j = 0; j < 4; j++) acc[i][j] = (floatx4){0.f, 0.f, 0.f, 0.f};

  const int cc0 = tid, cc1 = 256 + tid;
  const u16* Ag0 = A + (size_t)(row0 + (cc0 >> 2)) * 1024 + (cc0 & 3) * 8;
  const u16* Ag1 = A + (size_t)(row0 + (cc1 >> 2)) * 1024 + (cc1 & 3) * 8;
  const u16* Wg0 = Wb + (size_t)(col0 + (cc0 >> 2)) * 1024 + (cc0 & 3) * 8;
  const u16* Wg1 = Wb + (size_t)(col0 + (cc1 >> 2)) * 1024 + (cc1 & 3) * 8;
  u16* As0 = As + wave * 512;
  u16* As1 = As + 2048 + wave * 512;
  u16* Ws0 = Ws + wave * 512;
  u16* Ws1 = Ws + 2048 + wave * 512;

  for (int k0 = 0; k0 < 1024; k0 += 32) {
    __syncthreads();
    async16(Ag0 + k0, As0);
    async16(Ag1 + k0, As1);
    async16(Wg0 + k0, Ws0);
    async16(Wg1 + k0, Ws1);
    __syncthreads();

    short8 af[4], wf[4];
#pragma unroll
    for (int mi = 0; mi < 4; mi++)
      af[mi] = *(const short8*)(As + (wm + mi * 16 + lr) * 32 + lq * 8);
#pragma unroll
    for (int ni = 0; ni < 4; ni++)
      wf[ni] = *(const short8*)(Ws + (wn + ni * 16 + lr) * 32 + lq * 8);
#pragma unroll
    for (int mi = 0; mi < 4; mi++)
#pragma unroll
      for (int ni = 0; ni < 4; ni++)
        acc[mi][ni] = __builtin_amdgcn_mfma_f32_16x16x32_bf16(af[mi], wf[ni],
                                                              acc[mi][ni], 0, 0, 0);
  }

#pragma unroll
  for (int ni = 0; ni < 4; ni++) {
    const int col = col0 + wn + ni * 16 + lr;
    const float bv = bias[col];
#pragma unroll
    for (int mi = 0; mi < 4; mi++) {
#pragma unroll
      for (int r = 0; r < 4; r++) {
        const int row = row0 + wm + mi * 16 + lq * 4 + r;
        const float v = (acc[mi][ni][r] + bv) * scale;
        if (OUT == 0) {
          const int b = row >> 10, l = row & 1023, h = col >> 6, dh = col & 63;
          ((u16*)outv)[((b * HH + h) * LL + l) * DHH + dh] = f2b(v);
        } else if (OUT == 2) {
          const int b = row >> 10, l = row & 1023, h = col >> 6, dh = col & 63;
          ((u16*)outv)[((b * HH + h) * DHH + dh) * LL + l] = f2b(v);
        } else {
          ((float*)outv)[(size_t)row * 1024 + col] = v;
        }
      }
    }
  }
}

// Flash attention, transposed-S formulation with K-relabeling (no P shuffle):
//   S^T = mfma(kf, qf)  -> lane holds 16 S values for q = lane&15
//   softmax in-register; cross-lane reduce via __shfl_xor(16/32) (certain semantics)
//   P fragment: direct f2b of S in place. MFMA contracts slot-by-slot, so we
//   relabel the key axis: slot (lq, j) <-> key kappa = 32kk + 16*(j>>2) + 4*lq + (j&3).
//   V is read with the SAME kappa: two ds_read_b64 per (ni,kk) -> vf matches pf.
//   O^T = mfma(vf, pf)  -> Oacc col = q = lane&15 (alpha broadcast, no redistrib).
// K/V LDS tiles XOR-swizzled at 16B-granule level (pre-swizzled global source for
// global_load_lds; swizzled granule on read) -> LDS bandwidth floor, no conflicts.
__global__ __launch_bounds__(256) void attn_fast(
    const u16* __restrict__ qbuf, const u16* __restrict__ kbuf,
    const u16* __restrict__ vbt, const u32* __restrict__ maskb,
    const u32* __restrict__ amaskb, u16* __restrict__ ctx,
    float* __restrict__ top) {
  __shared__ u16 Ks[64 * 64];
  __shared__ u16 Vts[64 * 64];   // [dh][key], granule-swizzled

  // XCD-aware decode: all 8 qt-tiles of one (b,h) land on one XCD (id%8 const),
  // and the heavier h==0 (top-writer) blocks spread across XCDs via b.
  const int id = blockIdx.x;
  const int xcd = id & 7;
  const int r_ = id >> 3;
  const int b = r_ & 7;
  const int h = (((r_ >> 3) & 1) << 3) | (xcd ^ b);
  const int qt = r_ >> 4;

  const int tid = threadIdx.x, wave = tid >> 6, lane = tid & 63;
  const int lr = lane & 15, lq = lane >> 4;
  const int lq4 = lq * 4;
  const int x7 = lr & 7;

  const u16* Qg = qbuf + (size_t)((b * HH + h) * LL + qt * 128) * DHH;
  const u16* Kg = kbuf + (size_t)((b * HH + h) * LL) * DHH;
  const u16* Vtg = vbt + (size_t)((b * HH + h) * DHH) * LL;  // [dh][l]

  // Q fragments hoisted to registers (B-operand cols = q over lr): 16 VGPRs.
  short8 qf[2][2];
#pragma unroll
  for (int mi = 0; mi < 2; mi++)
#pragma unroll
    for (int kk = 0; kk < 2; kk++)
      qf[mi][kk] = *(const short8*)(Qg + (wave * 32 + mi * 16 + lr) * 64 +
                                    kk * 32 + lq * 8);

  // Staging granule g. LDS granule g holds global chunk (row = g>>3,
  // col = (g&7) ^ (row&7)) -> pre-swizzled per-lane global source address.
  const int g0 = tid, g1 = 256 + tid;
  const int kr0 = g0 >> 3, kc0 = (g0 & 7) ^ (kr0 & 7);
  const int kr1 = g1 >> 3, kc1 = (g1 & 7) ^ (kr1 & 7);
  // K read (b128): global granule c_want = 4*kk + lq -> LDS col = c_want ^ (row&7)
  const int cs0 = ((0 + lq) ^ x7) * 8;
  const int cs1 = ((4 + lq) ^ x7) * 8;
  // V read (2x b64 per kk): keys 32kk+4lq+0..3 (lo) and +16 (hi):
  //   granule = 4kk + 2*(hi) + (lq>>1), intra-granule u16 offset = 4*(lq&1)
  const int lqh = lq >> 1, lqb = (lq & 1) * 4;
  const int go00 = ((0 + lqh) ^ x7) * 8 + lqb;  // kk=0 lo
  const int go01 = ((2 + lqh) ^ x7) * 8 + lqb;  // kk=0 hi
  const int go10 = ((4 + lqh) ^ x7) * 8 + lqb;  // kk=1 lo
  const int go11 = ((6 + lqh) ^ x7) * 8 + lqb;  // kk=1 hi

  float mrow[2], lrow[2];
  floatx4 Oacc[2][4];
#pragma unroll
  for (int mi = 0; mi < 2; mi++) {
    mrow[mi] = NEGBIG;
    lrow[mi] = 0.f;
#pragma unroll
    for (int ni = 0; ni < 4; ni++) Oacc[mi][ni] = (floatx4){0.f, 0.f, 0.f, 0.f};
  }

  for (int kc = 0; kc < 16; kc++) {
    __syncthreads();
    async16(Kg + kc * 4096 + kr0 * 64 + kc0 * 8, Ks + wave * 512);
    async16(Kg + kc * 4096 + kr1 * 64 + kc1 * 8, Ks + 2048 + wave * 512);
    async16(Vtg + (size_t)kr0 * LL + kc * 64 + kc0 * 8, Vts + wave * 512);
    async16(Vtg + (size_t)kr1 * LL + kc * 64 + kc1 * 8, Vts + 2048 + wave * 512);
    __syncthreads();

    // QK^T swapped: S[mi][nj][r] = S(k = nj*16 + lq*4 + r, q = mi*16 + lr)
    floatx4 S[2][4];
#pragma unroll
    for (int nj = 0; nj < 4; nj++) {
      const short8 kf0 = *(const short8*)(Ks + (nj * 16 + lr) * 64 + cs0);
      const short8 kf1 = *(const short8*)(Ks + (nj * 16 + lr) * 64 + cs1);
#pragma unroll
      for (int mi = 0; mi < 2; mi++) {
        floatx4 z = (floatx4){0.f, 0.f, 0.f, 0.f};
        z = __builtin_amdgcn_mfma_f32_16x16x32_bf16(kf1, qf[mi][1], z, 0, 0, 0);
        z = __builtin_amdgcn_mfma_f32_16x16x32_bf16(kf0, qf[mi][0], z, 0, 0, 0);
        S[mi][nj] = z;
      }
    }

    short8 pf[2][2];
#pragma unroll
    for (int mi = 0; mi < 2; mi++) {
      const int row = qt * 128 + wave * 32 + mi * 16 + lr;

      if (h == 0) {  // raw scores, pre-mask; r=0..3 are consecutive k -> float4
        float* tp = top + (size_t)(b * LL + row) * LL + kc * 64 + lq4;
#pragma unroll
        for (int nj = 0; nj < 4; nj++) {
          float4 t;
          t.x = S[mi][nj][0]; t.y = S[mi][nj][1];
          t.z = S[mi][nj][2]; t.w = S[mi][nj][3];
          *(float4*)(tp + nj * 16) = t;
        }
      }

      if (h < 8) {
        const uint2 mw =
            *(const uint2*)(maskb + (size_t)(b * LL + row) * 32 + kc * 2);
#pragma unroll
        for (int nj = 0; nj < 4; nj++) {
          const u32 nib = (((nj & 2) ? mw.y : mw.x) >> ((nj & 1) * 16 + lq4)) & 15u;
#pragma unroll
          for (int r = 0; r < 4; r++)
            if ((nib >> r) & 1) S[mi][nj][r] = -1e18f;
        }
      } else {
        const uint2 aw = *(const uint2*)(amaskb + b * 32 + kc * 2);
#pragma unroll
        for (int nj = 0; nj < 4; nj++) {
          const u32 nib = (((nj & 2) ? aw.y : aw.x) >> ((nj & 1) * 16 + lq4)) & 15u;
#pragma unroll
          for (int r = 0; r < 4; r++)
            if ((nib >> r) & 1) S[mi][nj][r] = -1e18f;
        }
      }

      // online softmax for q = lr: 16 in-register + 2 shfl_xor butterfly steps
      float cm = fmaxf(fmaxf(S[mi][0][0], S[mi][0][1]),
                       fmaxf(S[mi][0][2], S[mi][0][3]));
#pragma unroll
      for (int nj = 1; nj < 4; nj++)
        cm = fmaxf(cm, fmaxf(fmaxf(S[mi][nj][0], S[mi][nj][1]),
                             fmaxf(S[mi][nj][2], S[mi][nj][3])));
      cm = fmaxf(cm, __shfl_xor(cm, 16, 64));
      cm = fmaxf(cm, __shfl_xor(cm, 32, 64));
      const float mold = mrow[mi];
      const float mnew = fmaxf(mold, cm);
      const float alpha = __expf(mold - mnew);
      mrow[mi] = mnew;
      float rs = 0.f;
#pragma unroll
      for (int nj = 0; nj < 4; nj++)
#pragma unroll
        for (int r = 0; r < 4; r++) {
          const float p = __expf(S[mi][nj][r] - mnew);
          S[mi][nj][r] = p;
          rs += p;
        }
      rs += __shfl_xor(rs, 16, 64);
      rs += __shfl_xor(rs, 32, 64);
      lrow[mi] = lrow[mi] * alpha + rs;
#pragma unroll
      for (int ni = 0; ni < 4; ni++)
#pragma unroll
        for (int r = 0; r < 4; r++) Oacc[mi][ni][r] *= alpha;

      // P fragment under key-relabeling kappa(lq,j) = 32kk + 16*(j>>2) + 4lq + (j&3):
      // no cross-lane movement -- just convert S in place.
#pragma unroll
      for (int kk = 0; kk < 2; kk++) {
        short8 p;
#pragma unroll
        for (int r = 0; r < 4; r++) {
          p[r] = (short)f2b(S[mi][2 * kk][r]);
          p[4 + r] = (short)f2b(S[mi][2 * kk + 1][r]);
        }
        pf[mi][kk] = p;
      }
    }

    // PV: O^T accumulation; V read with the same kappa so slots pair with pf.
#pragma unroll
    for (int ni = 0; ni < 4; ni++) {
      const int rb = (ni * 16 + lr) * 64;
      const short4v v00 = *(const short4v*)(Vts + rb + go00);
      const short4v v01 = *(const short4v*)(Vts + rb + go01);
      const short4v v10 = *(const short4v*)(Vts + rb + go10);
      const short4v v11 = *(const short4v*)(Vts + rb + go11);
      const short8 vf0 = __builtin_shufflevector(v00, v01, 0, 1, 2, 3, 4, 5, 6, 7);
      const short8 vf1 = __builtin_shufflevector(v10, v11, 0, 1, 2, 3, 4, 5, 6, 7);
#pragma unroll
      for (int mi = 0; mi < 2; mi++) {
        Oacc[mi][ni] =
            __builtin_amdgcn_mfma_f32_16x16x32_bf16(vf0, pf[mi][0], Oacc[mi][ni], 0, 0, 0);
        Oacc[mi][ni] =
            __builtin_amdgcn_mfma_f32_16x16x32_bf16(vf1, pf[mi][1], Oacc[mi][ni], 0, 0, 0);
      }
    }
  }

#pragma unroll
  for (int mi = 0; mi < 2; mi++) {
    const float inv = 1.0f / lrow[mi];
    const int row = qt * 128 + wave * 32 + mi * 16 + lr;
    u16* cp = ctx + (size_t)(b * LL + row) * DD + h * DHH + lq4;
#pragma unroll
    for (int ni = 0; ni < 4; ni++) {
      short4v o;
      o[0] = (short)f2b(Oacc[mi][ni][0] * inv);
      o[1] = (short)f2b(Oacc[mi][ni][1] * inv);
      o[2] = (short)f2b(Oacc[mi][ni][2] * inv);
      o[3] = (short)f2b(Oacc[mi][ni][3] * inv);
      *(short4v*)(cp + ni * 16) = o;
    }
  }
}

// ===========================================================================
// FALLBACK PATH (R5-proven, 64 MB ws)
// ===========================================================================
template <int MODE>
__global__ __launch_bounds__(256) void gemm_k(
    const void* __restrict__ Av, const float* __restrict__ W,
    const float* __restrict__ biasp, void* __restrict__ outv, float scale) {
  __shared__ u16 As[128 * 32];
  __shared__ u16 Ws[128 * 32];
  const int tid = threadIdx.x;
  const int wave = tid >> 6, lane = tid & 63;
  const int lr = lane & 15, lq = lane >> 4;
  const int row0 = blockIdx.x * 128;
  const int col0 = blockIdx.y * 128;
  const int wm = (wave & 1) * 64, wn = (wave >> 1) * 64;
  floatx4 acc[4][4];
#pragma unroll
  for (int i = 0; i < 4; i++)
#pragma unroll
    for (int j = 0; j < 4; j++) acc[i][j] = (floatx4){0.f, 0.f, 0.f, 0.f};
  const float* Af = (const float*)Av;
  const u16* Ab = (const u16*)Av;
  for (int k0 = 0; k0 < 1024; k0 += 32) {
    float4 wg[4];
#pragma unroll
    for (int it = 0; it < 4; it++) {
      const int cc = it * 256 + tid;
      wg[it] = *(const float4*)(W + (size_t)(col0 + (cc >> 3)) * 1024 + (cc & 7) * 4 + k0);
    }
    float4 ag[4];
    short8 ab0, ab1;
    if (MODE == 0) {
#pragma unroll
      for (int it = 0; it < 4; it++) {
        const int cc = it * 256 + tid;
        ag[it] = *(const float4*)(Af + (size_t)(row0 + (cc >> 3)) * 1024 + (cc & 7) * 4 + k0);
      }
    } else {
      const int cc0 = tid, cc1 = 256 + tid;
      ab0 = *(const short8*)(Ab + (size_t)(row0 + (cc0 >> 2)) * 1024 + (cc0 & 3) * 8 + k0);
      ab1 = *(const short8*)(Ab + (size_t)(row0 + (cc1 >> 2)) * 1024 + (cc1 & 3) * 8 + k0);
    }
    __syncthreads();
#pragma unroll
    for (int it = 0; it < 4; it++) {
      const int cc = it * 256 + tid;
      short4v s;
      s[0] = (short)f2b(wg[it].x); s[1] = (short)f2b(wg[it].y);
      s[2] = (short)f2b(wg[it].z); s[3] = (short)f2b(wg[it].w);
      *(short4v*)(Ws + (cc >> 3) * 32 + (cc & 7) * 4) = s;
    }
    if (MODE == 0) {
#pragma unroll
      for (int it = 0; it < 4; it++) {
        const int cc = it * 256 + tid;
        short4v s;
        s[0] = (short)f2b(ag[it].x); s[1] = (short)f2b(ag[it].y);
        s[2] = (short)f2b(ag[it].z); s[3] = (short)f2b(ag[it].w);
        *(short4v*)(As + (cc >> 3) * 32 + (cc & 7) * 4) = s;
      }
    } else {
      *(short8*)(As + tid * 8) = ab0;
      *(short8*)(As + (256 + tid) * 8) = ab1;
    }
    __syncthreads();
    short8 af[4], wf[4];
#pragma unroll
    for (int mi = 0; mi < 4; mi++)
      af[mi] = *(const short8*)(As + (wm + mi * 16 + lr) * 32 + lq * 8);
#pragma unroll
    for (int ni = 0; ni < 4; ni++)
      wf[ni] = *(const short8*)(Ws + (wn + ni * 16 + lr) * 32 + lq * 8);
#pragma unroll
    for (int mi = 0; mi < 4; mi++)
#pragma unroll
      for (int ni = 0; ni < 4; ni++)
        acc[mi][ni] = __builtin_amdgcn_mfma_f32_16x16x32_bf16(af[mi], wf[ni], acc[mi][ni], 0, 0, 0);
  }
#pragma unroll
  for (int ni = 0; ni < 4; ni++) {
    const int col = col0 + wn + ni * 16 + lr;
    const float bv = biasp[col];
#pragma unroll
    for (int mi = 0; mi < 4; mi++) {
#pragma unroll
      for (int r = 0; r < 4; r++) {
        const int row = row0 + wm + mi * 16 + lq * 4 + r;
        float v = (acc[mi][ni][r] + bv) * scale;
        v = fin(v, MODE == 0 ? 700.0f : 1000.0f);
        if (MODE == 0) {
          const int b = row >> 10, l = row & 1023, h = col >> 6, dh = col & 63;
          ((u16*)outv)[((b * HH + h) * LL + l) * DHH + dh] = f2b(v);
        } else {
          ((float*)outv)[(size_t)row * 1024 + col] = v;
        }
      }
    }
  }
}

__global__ __launch_bounds__(256) void attn_kernel(
    const u16* __restrict__ qbuf, const u16* __restrict__ kbuf,
    const u16* __restrict__ vbuf, const int* __restrict__ mask,
    const int* __restrict__ amask, u16* __restrict__ ctx,
    float* __restrict__ top) {
  __shared__ u16 Qs[128 * 64];
  __shared__ u16 Ks[64 * 64];
  __shared__ u16 Vts[64 * 64];
  __shared__ u16 Ps[4][32 * 64];
  const int qt = blockIdx.x, h = blockIdx.y, b = blockIdx.z;
  const int tid = threadIdx.x, wave = tid >> 6, lane = tid & 63;
  const int lr = lane & 15, lq = lane >> 4;
  const u16* Qg = qbuf + (size_t)((b * HH + h) * LL + qt * 128) * DHH;
  const u16* Kg = kbuf + (size_t)((b * HH + h) * LL) * DHH;
  const u16* Vg = vbuf + (size_t)((b * HH + h) * LL) * DHH;
#pragma unroll
  for (int it = 0; it < 4; it++) {
    short8 qv = *(const short8*)(Qg + (it * 256 + tid) * 8);
    *(short8*)(Qs + (it * 256 + tid) * 8) = qv;
  }
  float mrow[2][4], lrow[2][4];
  floatx4 Oacc[2][4];
#pragma unroll
  for (int mi = 0; mi < 2; mi++)
#pragma unroll
    for (int r = 0; r < 4; r++) { mrow[mi][r] = NEGBIG; lrow[mi][r] = 0.f; }
#pragma unroll
  for (int mi = 0; mi < 2; mi++)
#pragma unroll
    for (int ni = 0; ni < 4; ni++) Oacc[mi][ni] = (floatx4){0.f, 0.f, 0.f, 0.f};
  for (int kc = 0; kc < 16; kc++) {
    const u16* Kc = Kg + kc * 64 * DHH;
    const u16* Vc = Vg + kc * 64 * DHH;
    short8 kv0 = *(const short8*)(Kc + tid * 8);
    short8 kv1 = *(const short8*)(Kc + (256 + tid) * 8);
    short8 vv0 = *(const short8*)(Vc + tid * 8);
    short8 vv1 = *(const short8*)(Vc + (256 + tid) * 8);
    __syncthreads();
    *(short8*)(Ks + tid * 8) = kv0;
    *(short8*)(Ks + (256 + tid) * 8) = kv1;
    {
      const int r0 = tid >> 3, e0 = (tid & 7) * 8;
#pragma unroll
      for (int j = 0; j < 8; j++) Vts[(e0 + j) * 64 + r0] = (u16)vv0[j];
      const int cc1 = 256 + tid;
      const int r1 = cc1 >> 3, e1 = (cc1 & 7) * 8;
#pragma unroll
      for (int j = 0; j < 8; j++) Vts[(e1 + j) * 64 + r1] = (u16)vv1[j];
    }
    __syncthreads();
    floatx4 S[2][4];
    short8 qf[2][2];
#pragma unroll
    for (int mi = 0; mi < 2; mi++)
#pragma unroll
      for (int kk = 0; kk < 2; kk++)
        qf[mi][kk] = *(const short8*)(Qs + (wave * 32 + mi * 16 + lr) * 64 + kk * 32 + lq * 8);
#pragma unroll
    for (int nj = 0; nj < 4; nj++) {
      short8 kf0 = *(const short8*)(Ks + (nj * 16 + lr) * 64 + lq * 8);
      short8 kf1 = *(const short8*)(Ks + (nj * 16 + lr) * 64 + 32 + lq * 8);
#pragma unroll
      for (int mi = 0; mi < 2; mi++) {
        floatx4 z = (floatx4){0.f, 0.f, 0.f, 0.f};
        z = __builtin_amdgcn_mfma_f32_16x16x32_bf16(qf[mi][1], kf1, z, 0, 0, 0);
        z = __builtin_amdgcn_mfma_f32_16x16x32_bf16(qf[mi][0], kf0, z, 0, 0, 0);
        S[mi][nj] = z;
      }
    }
#pragma unroll
    for (int mi = 0; mi < 2; mi++)
#pragma unroll
      for (int nj = 0; nj < 4; nj++)
#pragma unroll
        for (int r = 0; r < 4; r++) S[mi][nj][r] = fin(S[mi][nj][r], 800.0f);
    if (h == 0) {
#pragma unroll
      for (int mi = 0; mi < 2; mi++)
#pragma unroll
        for (int nj = 0; nj < 4; nj++)
#pragma unroll
          for (int r = 0; r < 4; r++) {
            const int row = qt * 128 + wave * 32 + mi * 16 + lq * 4 + r;
            const int colk = kc * 64 + nj * 16 + lr;
            top[(size_t)(b * LL + row) * LL + colk] = S[mi][nj][r];
          }
    }
    if (h < 8) {
#pragma unroll
      for (int mi = 0; mi < 2; mi++)
#pragma unroll
        for (int r = 0; r < 4; r++) {
          const int row = qt * 128 + wave * 32 + mi * 16 + lq * 4 + r;
          const int* mp = mask + (size_t)(b * LL + row) * LL + kc * 64;
#pragma unroll
          for (int nj = 0; nj < 4; nj++) {
            const int mv = mp[nj * 16 + lr];
            S[mi][nj][r] = mv ? -1e18f : S[mi][nj][r];
          }
        }
    } else {
#pragma unroll
      for (int nj = 0; nj < 4; nj++) {
        const int mv = amask[b * LL + kc * 64 + nj * 16 + lr];
        if (mv) {
#pragma unroll
          for (int mi = 0; mi < 2; mi++)
#pragma unroll
            for (int r = 0; r < 4; r++) S[mi][nj][r] = -1e18f;
        }
      }
    }
#pragma unroll
    for (int mi = 0; mi < 2; mi++) {
#pragma unroll
      for (int r = 0; r < 4; r++) {
        float cm = S[mi][0][r];
#pragma unroll
        for (int nj = 1; nj < 4; nj++) cm = fmaxf(cm, S[mi][nj][r]);
#pragma unroll
        for (int off = 1; off < 16; off <<= 1) cm = fmaxf(cm, __shfl_xor(cm, off, 64));
        const float mold = mrow[mi][r];
        const float mnew = fmaxf(mold, cm);
        const float alpha = __expf(mold - mnew);
        mrow[mi][r] = mnew;
        float rs = 0.f;
#pragma unroll
        for (int nj = 0; nj < 4; nj++) {
          const float p = __expf(S[mi][nj][r] - mnew);
          S[mi][nj][r] = p;
          rs += p;
        }
#pragma unroll
        for (int off = 1; off < 16; off <<= 1) rs += __shfl_xor(rs, off, 64);
        lrow[mi][r] = lrow[mi][r] * alpha + rs;
#pragma unroll
        for (int ni = 0; ni < 4; ni++) Oacc[mi][ni][r] *= alpha;
      }
    }
#pragma unroll
    for (int mi = 0; mi < 2; mi++)
#pragma unroll
      for (int nj = 0; nj < 4; nj++)
#pragma unroll
        for (int r = 0; r < 4; r++)
          Ps[wave][(mi * 16 + lq * 4 + r) * 64 + nj * 16 + lr] = f2b(S[mi][nj][r]);
    __syncthreads();
#pragma unroll
    for (int kk = 0; kk < 2; kk++) {
      short8 pf[2];
#pragma unroll
      for (int mi = 0; mi < 2; mi++)
        pf[mi] = *(const short8*)(&Ps[wave][(mi * 16 + lr) * 64 + kk * 32 + lq * 8]);
#pragma unroll
      for (int ni = 0; ni < 4; ni++) {
        short8 vf = *(const short8*)(Vts + (ni * 16 + lr) * 64 + kk * 32 + lq * 8);
#pragma unroll
        for (int mi = 0; mi < 2; mi++)
          Oacc[mi][ni] = __builtin_amdgcn_mfma_f32_16x16x32_bf16(pf[mi], vf, Oacc[mi][ni], 0, 0, 0);
      }
    }
  }
#pragma unroll
  for (int mi = 0; mi < 2; mi++)
#pragma unroll
    for (int r = 0; r < 4; r++) {
      const float inv = 1.0f / lrow[mi][r];
      const int row = qt * 128 + wave * 32 + mi * 16 + lq * 4 + r;
#pragma unroll
      for (int ni = 0; ni < 4; ni++) {
        const int col = h * DHH + ni * 16 + lr;
        ctx[(size_t)(b * LL + row) * DD + col] = f2b(fin(Oacc[mi][ni][r] * inv, 900.0f));
      }
    }
}

// ===========================================================================
extern "C" void kernel_launch(void* const* d_in, const int* in_sizes, int n_in,
                              void* d_out, int out_size, void* d_ws, size_t ws_size,
                              hipStream_t stream) {
  const float* key   = (const float*)d_in[0];
  const float* value = (const float*)d_in[1];
  const float* query = (const float*)d_in[2];
  const int* mask    = (const int*)d_in[3];
  const int* amask   = (const int*)d_in[4];
  const float* Wk = (const float*)d_in[5];
  const float* bk = (const float*)d_in[6];
  const float* Wv = (const float*)d_in[7];
  const float* bv = (const float*)d_in[8];
  const float* Wq = (const float*)d_in[9];
  const float* bq = (const float*)d_in[10];
  const float* Wo = (const float*)d_in[11];
  const float* bo = (const float*)d_in[12];

  float* outp = (float*)d_out;                  // out (B,L,D) f32
  float* topp = outp + (size_t)BB * LL * DD;    // top_score (B,L,L) f32

  const size_t M8 = (size_t)BB * LL * DD;       // 8M elems
  const size_t M1 = (size_t)DD * DD;            // 1M elems
  const size_t NEED = (size_t)90 * 1024 * 1024; // fast-path ws bytes

  dim3 tb(256), gg(64, 8, 1), ga(8, 16, 8);

  if (ws_size >= NEED) {
    u16* W16 = (u16*)d_ws;
    u16* keyb = W16;               // conv..gemmK; reused as qbuf
    u16* valb = W16 + M8;          // conv..gemmV; reused as cbuf
    u16* qryb = W16 + 2 * M8;      // conv..gemmQ
    u16* Wkb = W16 + 3 * M8;
    u16* Wvb = Wkb + M1;
    u16* Wqb = Wvb + M1;
    u16* Wob = Wqb + M1;
    u32* maskb = (u32*)(Wob + M1);               // 1 MB
    u32* amaskb = maskb + 262144;                // 1 KB
    u16* kbuf = W16 + 3 * M8 + 5 * M1;           // masks fit in the 5th M1
    u16* vbt  = kbuf + M8;
    u16* qbuf = keyb;
    u16* cbuf = valb;

    convpack<<<dim3(256, 9), tb, 0, stream>>>(
        key, value, query, Wk, Wv, Wq, Wo, mask, amask,
        keyb, valb, qryb, Wkb, Wvb, Wqb, Wob, maskb, amaskb);
    gemm_b<0><<<gg, tb, 0, stream>>>(keyb, Wkb, bk, kbuf, 1.0f);
    gemm_b<2><<<gg, tb, 0, stream>>>(valb, Wvb, bv, vbt, 1.0f);
    gemm_b<0><<<gg, tb, 0, stream>>>(qryb, Wqb, bq, qbuf, 0.125f);
    attn_fast<<<dim3(1024, 1, 1), tb, 0, stream>>>(qbuf, kbuf, vbt, maskb,
                                                   amaskb, cbuf, topp);
    gemm_b<1><<<gg, tb, 0, stream>>>(cbuf, Wob, bo, outp, 1.0f);
  } else {
    u16* kbuf = (u16*)d_ws;
    u16* vbuf = kbuf + M8;
    u16* qbuf = vbuf + M8;
    u16* cbuf = qbuf + M8;
    gemm_k<0><<<gg, tb, 0, stream>>>(key,   Wk, bk, kbuf, 1.0f);
    gemm_k<0><<<gg, tb, 0, stream>>>(value, Wv, bv, vbuf, 1.0f);
    gemm_k<0><<<gg, tb, 0, stream>>>(query, Wq, bq, qbuf, 0.125f);
    attn_kernel<<<ga, tb, 0, stream>>>(qbuf, kbuf, vbuf, mask, amask, cbuf, topp);
    gemm_k<1><<<gg, tb, 0, stream>>>(cbuf, Wo, bo, outp, 1.0f);
  }
}